// Round 2
// baseline (41.453 us; speedup 1.0000x reference)
//
#include <hip/hip_runtime.h>
#include <hip/hip_bf16.h>
#include <math.h>

// Problem constants (from setup_inputs): B=1, C=256, H=W=50, N=256 boxes, OUT=7
#define RC    256
#define RH    50
#define RW    50
#define RN    256
#define ROUT  7
#define NBINS 49   // 7*7
#define HW    (RH * RW)

// featT[hw][c] = feat[c][hw]  — makes channels contiguous per pixel.
__global__ void __launch_bounds__(256)
transpose_kernel(const float* __restrict__ feat, float* __restrict__ featT) {
    int idx = blockIdx.x * 256 + threadIdx.x;   // total = HW*RC = 640000, exact
    int c  = idx & (RC - 1);
    int hw = idx >> 8;
    featT[idx] = feat[c * HW + hw];
}

// One wave per (box, bin). Lane owns 4 channels (float4).
__global__ void __launch_bounds__(256)
pool_kernel(const float* __restrict__ featT,
            const float* __restrict__ boxes,
            const int* __restrict__ image_size_p,
            float* __restrict__ out) {
    int lane = threadIdx.x & 63;
    int wv   = threadIdx.x >> 6;          // wave index in block: 0..3
    int b    = blockIdx.x;                // 0 .. 256*13-1
    int n    = b / 13;
    int bin  = (b % 13) * 4 + wv;         // 0..51
    if (bin >= NBINS) return;
    int ky = bin / ROUT;
    int kx = bin % ROUT;

    float im = (float)(*image_size_p);
    float scale_w = (float)RW / im;
    float scale_h = (float)RH / im;

    float bx = boxes[n * 4 + 0];
    float by = boxes[n * 4 + 1];
    float bw = boxes[n * 4 + 2];
    float bh = boxes[n * 4 + 3];
    bool bad = (bw <= 0.0f) || (bh <= 0.0f);

    float x1f = (bad ? 0.25f * im : bx) * scale_w;
    float x2f = (bad ? 0.75f * im : bx + bw) * scale_w;
    float y1f = (bad ? 0.25f * im : by) * scale_h;
    float y2f = (bad ? 0.75f * im : by + bh) * scale_h;

    int x1 = max(0, (int)x1f);
    int y1 = max(0, (int)y1f);
    int x2 = min(RW, (int)x2f + 1);
    int y2 = min(RH, (int)y2f + 1);
    if (x2 <= x1 + 1) x2 = min(x1 + 2, RW);
    if (y2 <= y1 + 1) y2 = min(y1 + 2, RH);
    x1 = min(max(x1, 0), RW - 2);
    y1 = min(max(y1, 0), RH - 2);
    x2 = max(x1 + 1, min(x2, RW));
    y2 = max(y1 + 1, min(y2, RH));

    int szx = x2 - x1;
    int szy = y2 - y1;
    int sx = x1 + (kx * szx) / ROUT;
    int ex = x1 + ((kx + 1) * szx + ROUT - 1) / ROUT;
    int sy = y1 + (ky * szy) / ROUT;
    int ey = y1 + ((ky + 1) * szy + ROUT - 1) / ROUT;

    int c0 = lane * 4;
    float mx_ = -INFINITY, my_ = -INFINITY, mz_ = -INFINITY, mw_ = -INFINITY;
    for (int y = sy; y < ey; ++y) {
        const float* __restrict__ rowp = featT + (y * RW) * RC + c0;
        for (int x = sx; x < ex; ++x) {
            float4 v = *(const float4*)(rowp + x * RC);
            mx_ = fmaxf(mx_, v.x);
            my_ = fmaxf(my_, v.y);
            mz_ = fmaxf(mz_, v.z);
            mw_ = fmaxf(mw_, v.w);
        }
    }

    float* o = out + n * (RC * NBINS) + bin;
    o[(c0 + 0) * NBINS] = mx_;
    o[(c0 + 1) * NBINS] = my_;
    o[(c0 + 2) * NBINS] = mz_;
    o[(c0 + 3) * NBINS] = mw_;
}

extern "C" void kernel_launch(void* const* d_in, const int* in_sizes, int n_in,
                              void* d_out, int out_size, void* d_ws, size_t ws_size,
                              hipStream_t stream) {
    const float* feat  = (const float*)d_in[0];
    const float* boxes = (const float*)d_in[1];
    const int* im_sz   = (const int*)d_in[2];
    float* out   = (float*)d_out;
    float* featT = (float*)d_ws;          // 2.56 MB out of ~256 MB scratch

    transpose_kernel<<<HW, 256, 0, stream>>>(feat, featT);

    const int grid = RN * 13;             // 13 wave-groups of 4 cover 49 bins
    pool_kernel<<<grid, 256, 0, stream>>>(featT, boxes, im_sz, out);
}